// Round 10
// baseline (228.564 us; speedup 1.0000x reference)
//
#include <hip/hip_runtime.h>
#include <stdint.h>
#include <stddef.h>

// Problem constants
#define SEQ   2048
#define DIM   1024
#define NH    16
#define HD    64
#define MTOT  4096   // B*S
#define LPAD  72     // LDS row stride (shorts): 144B = +4 banks/row
#define EPAD  136    // epilogue bf16 tile stride (shorts)
#define FPAD  132    // epilogue fp32 slab stride (floats)

typedef __attribute__((ext_vector_type(8))) short short8;         // 8 bf16 = 4 VGPRs
typedef __attribute__((ext_vector_type(4))) float floatx4;        // MFMA C/D
typedef __attribute__((ext_vector_type(4))) float float4v;
typedef __attribute__((ext_vector_type(4))) unsigned short ushort4v;

__device__ __forceinline__ floatx4 mfma_bf16(short8 a, short8 b, floatx4 c) {
    return __builtin_amdgcn_mfma_f32_16x16x32_bf16(a, b, c, 0, 0, 0);
}

__device__ __forceinline__ float b2f(unsigned short s) {
    unsigned int u = ((unsigned int)s) << 16;
    return __builtin_bit_cast(float, u);
}
__device__ __forceinline__ unsigned short f2b(float f) {  // RNE
    unsigned int u = __builtin_bit_cast(unsigned int, f);
    u += 0x7fffu + ((u >> 16) & 1u);
    return (unsigned short)(u >> 16);
}

// ---------------- weight transpose+convert: W[K][N] f32 -> WT[N][K] bf16 ----------------
__global__ __launch_bounds__(256) void transpose_all(const float* __restrict__ w0,
                                                     const float* __restrict__ w1,
                                                     const float* __restrict__ w2,
                                                     const float* __restrict__ w3,
                                                     unsigned short* __restrict__ outbase) {
    __shared__ float t[64][65];
    const int z = blockIdx.z;
    const float* in = (z == 0) ? w0 : (z == 1) ? w1 : (z == 2) ? w2 : w3;
    unsigned short* out = outbase + (size_t)z * DIM * DIM;
    const int c0 = blockIdx.x * 64, r0 = blockIdx.y * 64;
    const int x = threadIdx.x, y = threadIdx.y;  // (64,4)
#pragma unroll
    for (int i = 0; i < 64; i += 4)
        t[y + i][x] = in[(size_t)(r0 + y + i) * DIM + c0 + x];
    __syncthreads();
#pragma unroll
    for (int i = 0; i < 64; i += 4)
        out[(size_t)(c0 + y + i) * DIM + r0 + x] = f2b(t[x][y + i]);
}

// ---------------- GEMM: C[m][n] = sum_k A[m][k]*BT[n][k] + bias[n] ----------------
// 128x128 tile, 4 waves (2x2 of 64x64), BK=64, pipelined staging.
// QKV=1: A is fp32 X (converted to bf16 during LDS staging). Outputs:
//   z=0: Q bf16 [B,H,S,Hd]; z=1: KPACK (MFMA B-frag order); z=2: VPACK.
// QKV=0: A bf16, fp32 row-major [M][N] out (projection).
template<int QKV>
__global__ __launch_bounds__(256) void gemm_fused(const void* __restrict__ Av,
                                                  const unsigned short* __restrict__ WTbase,
                                                  const float* __restrict__ b0,
                                                  const float* __restrict__ b1,
                                                  const float* __restrict__ b2,
                                                  void* __restrict__ outbase) {
    __shared__ __attribute__((aligned(16))) unsigned short smem[2 * 128 * LPAD];  // 36864 B
    unsigned short* As = smem;
    unsigned short* Bs = smem + 128 * LPAD;

    const int z = blockIdx.z;
    const unsigned short* BT = WTbase + (size_t)z * (DIM * DIM);
    const float* bias        = (z == 0) ? b0 : (z == 1) ? b1 : b2;
    const int mode = QKV ? ((z == 0) ? 1 : (z == 1) ? 3 : 4) : 0;
    float* Cf          = (float*)outbase;
    unsigned short* Cb = (unsigned short*)outbase + (size_t)z * ((size_t)MTOT * DIM);

    const int tid = threadIdx.x;
    const int w = tid >> 6, lane = tid & 63;
    const int quad = lane >> 4, l16 = lane & 15;
    const int wm = w >> 1, wn = w & 1;
    const int m0 = blockIdx.y * 128, n0 = blockIdx.x * 128;
    const int bb = m0 >> 11;

    floatx4 acc[4][4];
#pragma unroll
    for (int mi = 0; mi < 4; ++mi)
#pragma unroll
        for (int ni = 0; ni < 4; ++ni) acc[mi][ni] = (floatx4)0.0f;

    const int srow = tid >> 3, scol = (tid & 7) * 8;  // staging: 8 threads/row

    const unsigned short* Ab = (const unsigned short*)Av;  // QKV=0
    const float*          Af = (const float*)Av;           // QKV=1

    short8  pa[4];
    float4v paf0[4], paf1[4];
    short8  pb[4];
#pragma unroll
    for (int ch = 0; ch < 4; ++ch) {
        if (QKV) {
            paf0[ch] = *(const float4v*)&Af[(size_t)(m0 + ch * 32 + srow) * DIM + scol];
            paf1[ch] = *(const float4v*)&Af[(size_t)(m0 + ch * 32 + srow) * DIM + scol + 4];
        } else {
            pa[ch] = *(const short8*)&Ab[(size_t)(m0 + ch * 32 + srow) * DIM + scol];
        }
        pb[ch] = *(const short8*)&BT[(size_t)(n0 + ch * 32 + srow) * DIM + scol];
    }

    for (int k0 = 0;; k0 += 64) {
#pragma unroll
        for (int ch = 0; ch < 4; ++ch) {
            if (QKV) {
                short8 s;
#pragma unroll
                for (int e = 0; e < 4; ++e) {
                    s[e]     = (short)f2b(paf0[ch][e]);
                    s[e + 4] = (short)f2b(paf1[ch][e]);
                }
                *(short8*)&As[(ch * 32 + srow) * LPAD + scol] = s;
            } else {
                *(short8*)&As[(ch * 32 + srow) * LPAD + scol] = pa[ch];
            }
            *(short8*)&Bs[(ch * 32 + srow) * LPAD + scol] = pb[ch];
        }
        __syncthreads();
        const bool more = (k0 + 64 < DIM);
        if (more) {  // prefetch AFTER barrier; overlapped by MFMA phase below
#pragma unroll
            for (int ch = 0; ch < 4; ++ch) {
                if (QKV) {
                    paf0[ch] = *(const float4v*)&Af[(size_t)(m0 + ch * 32 + srow) * DIM + k0 + 64 + scol];
                    paf1[ch] = *(const float4v*)&Af[(size_t)(m0 + ch * 32 + srow) * DIM + k0 + 64 + scol + 4];
                } else {
                    pa[ch] = *(const short8*)&Ab[(size_t)(m0 + ch * 32 + srow) * DIM + k0 + 64 + scol];
                }
                pb[ch] = *(const short8*)&BT[(size_t)(n0 + ch * 32 + srow) * DIM + k0 + 64 + scol];
            }
        }
#pragma unroll
        for (int kk = 0; kk < 2; ++kk) {
            short8 a[4], b[4];
#pragma unroll
            for (int mi = 0; mi < 4; ++mi)
                a[mi] = *(const short8*)&As[(wm * 64 + mi * 16 + l16) * LPAD + kk * 32 + quad * 8];
#pragma unroll
            for (int ni = 0; ni < 4; ++ni)
                b[ni] = *(const short8*)&Bs[(wn * 64 + ni * 16 + l16) * LPAD + kk * 32 + quad * 8];
#pragma unroll
            for (int mi = 0; mi < 4; ++mi)
#pragma unroll
                for (int ni = 0; ni < 4; ++ni)
                    acc[mi][ni] = mfma_bf16(a[mi], b[ni], acc[mi][ni]);
        }
        if (!more) break;
        __syncthreads();
    }

    float bvv[4];
#pragma unroll
    for (int ni = 0; ni < 4; ++ni) bvv[ni] = bias[n0 + wn * 64 + ni * 16 + l16];

    if (mode == 0) {
        // fp32 row-major out, 4 passes of 32 m-rows x 128 n staged in LDS
        float* T = (float*)smem;
        for (int p = 0; p < 4; ++p) {
            __syncthreads();
            if (wm == (p >> 1)) {
                const int mib = (p & 1) * 2;
#pragma unroll
                for (int mm = 0; mm < 2; ++mm)
#pragma unroll
                    for (int ni = 0; ni < 4; ++ni)
#pragma unroll
                        for (int r = 0; r < 4; ++r)
                            T[(mm * 16 + quad * 4 + r) * FPAD + wn * 64 + ni * 16 + l16] =
                                acc[mib + mm][ni][r] + bvv[ni];
            }
            __syncthreads();
#pragma unroll
            for (int it = 0; it < 4; ++it) {
                const int c = it * 256 + tid;
                const int row = c >> 5, nof = (c & 31) * 4;
                *(float4v*)&Cf[(size_t)(m0 + p * 32 + row) * DIM + n0 + nof] =
                    *(const float4v*)&T[row * FPAD + nof];
            }
        }
    } else if (mode == 1) {
        // Q: [B,H,S,Hd] bf16
        unsigned short* T = smem;
        __syncthreads();
#pragma unroll
        for (int mi = 0; mi < 4; ++mi)
#pragma unroll
            for (int ni = 0; ni < 4; ++ni)
#pragma unroll
                for (int r = 0; r < 4; ++r)
                    T[(wm * 64 + mi * 16 + quad * 4 + r) * EPAD + wn * 64 + ni * 16 + l16] =
                        f2b(acc[mi][ni][r] + bvv[ni]);
        __syncthreads();
#pragma unroll
        for (int it = 0; it < 8; ++it) {
            const int c = it * 256 + tid;
            const int seg = c >> 3, d8 = (c & 7) * 8;
            const int mm = seg >> 1, hseg = seg & 1;
            const int h = (n0 >> 6) + hseg;
            const int s = (m0 & (SEQ - 1)) + mm;
            *(short8*)&Cb[((size_t)(bb * NH + h) * SEQ + s) * HD + d8] =
                *(const short8*)&T[mm * EPAD + hseg * 64 + d8];
        }
    } else if (mode == 3) {
        // K -> KPACK: stage [s][h*64+d], then store B-frags (1KB coalesced each)
        unsigned short* T = smem;
        __syncthreads();
#pragma unroll
        for (int mi = 0; mi < 4; ++mi)
#pragma unroll
            for (int ni = 0; ni < 4; ++ni)
#pragma unroll
                for (int r = 0; r < 4; ++r)
                    T[(wm * 64 + mi * 16 + quad * 4 + r) * EPAD + wn * 64 + ni * 16 + l16] =
                        f2b(acc[mi][ni][r] + bvv[ni]);
        __syncthreads();
#pragma unroll
        for (int it = 0; it < 8; ++it) {
            const int f = it * 256 + tid;
            const int ln = f & 63, fragid = f >> 6;
            const int h2 = fragid >> 4, j2 = (fragid >> 3) & 1;
            const int ni = (fragid >> 1) & 3, kk = fragid & 1;
            const int l16f = ln & 15, quadf = ln >> 4;
            const short8 v = *(const short8*)&T[(j2 * 64 + ni * 16 + l16f) * EPAD +
                                               h2 * 64 + kk * 32 + quadf * 8];
            const int bh = bb * NH + (n0 >> 6) + h2;
            const int jg = ((m0 & (SEQ - 1)) >> 6) + j2;
            *(short8*)&Cb[(((size_t)bh * 32 + jg) * 8 + ni * 2 + kk) * 512 + ln * 8] = v;
        }
    } else {
        // V -> VPACK: stage transposed [h*64+d][s], then store PV B-frags
        unsigned short* T = smem;
        __syncthreads();
#pragma unroll
        for (int mi = 0; mi < 4; ++mi)
#pragma unroll
            for (int ni = 0; ni < 4; ++ni) {
                ushort4v pk;
#pragma unroll
                for (int r = 0; r < 4; ++r) pk[r] = f2b(acc[mi][ni][r] + bvv[ni]);
                *(ushort4v*)&T[(wn * 64 + ni * 16 + l16) * EPAD + wm * 64 + mi * 16 + quad * 4] = pk;
            }
        __syncthreads();
#pragma unroll
        for (int it = 0; it < 8; ++it) {
            const int f = it * 256 + tid;
            const int ln = f & 63, fragid = f >> 6;
            const int h2 = fragid >> 4, j2 = (fragid >> 3) & 1;
            const int ni = (fragid >> 1) & 3, kk = fragid & 1;
            const int l16f = ln & 15, quadf = ln >> 4;
            const short8 v = *(const short8*)&T[(h2 * 64 + ni * 16 + l16f) * EPAD +
                                               j2 * 64 + kk * 32 + quadf * 8];
            const int bh = bb * NH + (n0 >> 6) + h2;
            const int jg = ((m0 & (SEQ - 1)) >> 6) + j2;
            *(short8*)&Cb[(((size_t)bh * 32 + jg) * 8 + ni * 2 + kk) * 512 + ln * 8] = v;
        }
    }
}

// ---------------- causal flash attention — barrier-free, 1 wave per block ----------------
// K/V pre-packed in MFMA B-frag order; wave loads B-operands directly from
// global (1KB coalesced b128 per frag). No __syncthreads anywhere.
// grid (64 qchunks, 32 bh), qchunk reversed (heavy first). Wave owns 32
// queries; j-loop bound = its exact causal range (jend = qc>>1).
// Flat softmax: p = exp(s) (scores bounded), masked -> 0, scale folded into Q.
// l computed by an all-ones B-frag MFMA (row-sum of P) — no shuffles.
__global__ __launch_bounds__(64) void attn_fwd(const unsigned short* __restrict__ Q,
                                               const unsigned short* __restrict__ KP,
                                               const unsigned short* __restrict__ VP,
                                               unsigned short* __restrict__ O) {
    __shared__ __attribute__((aligned(16))) unsigned short Os[32 * LPAD];  // wave-private

    const int qc = (gridDim.x - 1) - blockIdx.x;  // 0..63, heavy first
    const int bh = blockIdx.y;
    const int lane = threadIdx.x;
    const int quad = lane >> 4, l16 = lane & 15;

    const unsigned short* Qh  = Q  + (size_t)bh * SEQ * HD;
    const unsigned short* KPh = KP + (size_t)bh * 32 * 4096;
    const unsigned short* VPh = VP + (size_t)bh * 32 * 4096;
    const int q0 = qc * 32;
    const int jend = qc >> 1;

    // Q fragments (A-layout), pre-scaled by Hd^-0.5 = 0.125 (exact pow2 in bf16)
    short8 qf[2][2];
#pragma unroll
    for (int mi = 0; mi < 2; ++mi)
#pragma unroll
        for (int kk = 0; kk < 2; ++kk) {
            short8 t = *(const short8*)(Qh + (size_t)(q0 + mi * 16 + l16) * HD + kk * 32 + quad * 8);
            short8 o;
#pragma unroll
            for (int e = 0; e < 8; ++e)
                o[e] = (short)f2b(b2f((unsigned short)t[e]) * 0.125f);
            qf[mi][kk] = o;
        }

    // all-ones B-frag (bf16 1.0 = 0x3F80) — layout-invariant
    short8 ones;
#pragma unroll
    for (int e = 0; e < 8; ++e) ones[e] = (short)0x3F80;

    floatx4 o_acc[2][4], l_acc[2];
#pragma unroll
    for (int mi = 0; mi < 2; ++mi) {
#pragma unroll
        for (int ni = 0; ni < 4; ++ni) o_acc[mi][ni] = (floatx4)0.0f;
        l_acc[mi] = (floatx4)0.0f;
    }

    for (int j = 0; j <= jend; ++j) {
        const unsigned short* kb = KPh + (size_t)j * 4096 + lane * 8;
        const unsigned short* vb = VPh + (size_t)j * 4096 + lane * 8;
        short8 kf[4][2], vf[4][2];
#pragma unroll
        for (int ni = 0; ni < 4; ++ni)
#pragma unroll
            for (int kk = 0; kk < 2; ++kk) {
                kf[ni][kk] = *(const short8*)(kb + (ni * 2 + kk) * 512);
                vf[ni][kk] = *(const short8*)(vb + (ni * 2 + kk) * 512);
            }

        // S = Q K^T: 32 queries x 64 keys
        floatx4 s_acc[2][4];
#pragma unroll
        for (int mi = 0; mi < 2; ++mi)
#pragma unroll
            for (int ni = 0; ni < 4; ++ni) s_acc[mi][ni] = (floatx4)0.0f;
#pragma unroll
        for (int kk = 0; kk < 2; ++kk)
#pragma unroll
            for (int ni = 0; ni < 4; ++ni)
#pragma unroll
                for (int mi = 0; mi < 2; ++mi)
                    s_acc[mi][ni] = mfma_bf16(qf[mi][kk], kf[ni][kk], s_acc[mi][ni]);

        // flat softmax + PV per m-tile (wave-private; no barriers, no shuffles)
#pragma unroll
        for (int mi = 0; mi < 2; ++mi) {
            float p[4][4];
#pragma unroll
            for (int r = 0; r < 4; ++r) {
                const int q = q0 + mi * 16 + quad * 4 + r;
#pragma unroll
                for (int ni = 0; ni < 4; ++ni) {
                    const int key = j * 64 + ni * 16 + l16;
                    p[ni][r] = (key > q) ? 0.0f : __expf(s_acc[mi][ni][r]);
                }
            }
            // P: C-layout regs -> wave-private LDS -> A-layout frags
#pragma unroll
            for (int ni = 0; ni < 4; ++ni)
#pragma unroll
                for (int r = 0; r < 4; ++r)
                    Os[(quad * 4 + r) * LPAD + ni * 16 + l16] = f2b(p[ni][r]);

#pragma unroll
            for (int kk = 0; kk < 2; ++kk) {
                const short8 pfrag = *(const short8*)&Os[l16 * LPAD + kk * 32 + quad * 8];
#pragma unroll
                for (int ni = 0; ni < 4; ++ni)
                    o_acc[mi][ni] = mfma_bf16(pfrag, vf[ni][kk], o_acc[mi][ni]);
                l_acc[mi] = mfma_bf16(pfrag, ones, l_acc[mi]);  // row-sums -> l
            }
        }
    }

    // O epilogue: normalize, stage [32 q][64 d], coalesced 16B stores
    float inv[2][4];
#pragma unroll
    for (int mi = 0; mi < 2; ++mi)
#pragma unroll
        for (int r = 0; r < 4; ++r) inv[mi][r] = 1.0f / l_acc[mi][r];
#pragma unroll
    for (int mi = 0; mi < 2; ++mi)
#pragma unroll
        for (int ni = 0; ni < 4; ++ni)
#pragma unroll
            for (int r = 0; r < 4; ++r)
                Os[(mi * 16 + quad * 4 + r) * LPAD + ni * 16 + l16] =
                    f2b(o_acc[mi][ni][r] * inv[mi][r]);
    const int bb = bh >> 4, h = bh & 15;
#pragma unroll
    for (int it = 0; it < 4; ++it) {
        const int row = it * 8 + (lane >> 3), d8 = (lane & 7) * 8;
        *(short8*)&O[(size_t)(bb * SEQ + q0 + row) * DIM + h * HD + d8] =
            *(const short8*)&Os[row * LPAD + d8];
    }
}

// ---------------- host launch ----------------
extern "C" void kernel_launch(void* const* d_in, const int* in_sizes, int n_in,
                              void* d_out, int out_size, void* d_ws, size_t ws_size,
                              hipStream_t stream) {
    // Reference dtypes are float32 — inputs and output are fp32.
    const float* X  = (const float*)d_in[0];
    const float* Wq = (const float*)d_in[1];
    const float* bq = (const float*)d_in[2];
    const float* Wk = (const float*)d_in[3];
    const float* bk = (const float*)d_in[4];
    const float* Wv = (const float*)d_in[5];
    const float* bv = (const float*)d_in[6];
    const float* Wo = (const float*)d_in[7];
    const float* bo = (const float*)d_in[8];

    unsigned short* ws = (unsigned short*)d_ws;
    const size_t WSZ = (size_t)DIM * DIM;    // 1M elems
    const size_t TSZ = (size_t)MTOT * DIM;   // 4M elems
    unsigned short* WqT = ws;                // 4 transposed weights (bf16), contiguous
    unsigned short* WoT = ws + 3 * WSZ;
    unsigned short* Qb  = ws + 4 * WSZ;      // Q [B,H,S,Hd]
    unsigned short* Kp  = Qb + TSZ;          // KPACK (B-frag order)
    unsigned short* Vp  = Kp + TSZ;          // VPACK (B-frag order)
    unsigned short* Ob  = Vp + TSZ;          // attn out [B,S,H*Hd] bf16
    // ws total: 4*2MB + 4*8MB = 40 MB

    transpose_all<<<dim3(16, 16, 4), dim3(64, 4), 0, stream>>>(Wq, Wk, Wv, Wo, WqT);

    // fused QKV projections (fp32 X converted in-kernel): Q / KPACK / VPACK
    gemm_fused<1><<<dim3(DIM / 128, MTOT / 128, 3), 256, 0, stream>>>(
        X, WqT, bq, bk, bv, (void*)Qb);

    // barrier-free attention, 1 wave per block
    attn_fwd<<<dim3(SEQ / 32, 2 * NH), 64, 0, stream>>>(Qb, Kp, Vp, Ob);

    // output projection -> fp32 d_out
    gemm_fused<0><<<dim3(DIM / 128, MTOT / 128, 1), 256, 0, stream>>>(
        Ob, WoT, bo, bo, bo, d_out);
}

// Round 11
// 202.748 us; speedup vs baseline: 1.1273x; 1.1273x over previous
//
#include <hip/hip_runtime.h>
#include <stdint.h>
#include <stddef.h>

// Problem constants
#define SEQ   2048
#define DIM   1024
#define NH    16
#define HD    64
#define MTOT  4096   // B*S
#define LPAD  72     // LDS row stride (shorts): 144B = +4 banks/row
#define EPAD  136    // epilogue bf16 tile stride (shorts)
#define FPAD  132    // epilogue fp32 slab stride (floats)

typedef __attribute__((ext_vector_type(8))) short short8;         // 8 bf16 = 4 VGPRs
typedef __attribute__((ext_vector_type(4))) float floatx4;        // MFMA C/D
typedef __attribute__((ext_vector_type(4))) float float4v;
typedef __attribute__((ext_vector_type(4))) unsigned short ushort4v;

__device__ __forceinline__ floatx4 mfma_bf16(short8 a, short8 b, floatx4 c) {
    return __builtin_amdgcn_mfma_f32_16x16x32_bf16(a, b, c, 0, 0, 0);
}

__device__ __forceinline__ float b2f(unsigned short s) {
    unsigned int u = ((unsigned int)s) << 16;
    return __builtin_bit_cast(float, u);
}
__device__ __forceinline__ unsigned short f2b(float f) {  // RNE
    unsigned int u = __builtin_bit_cast(unsigned int, f);
    u += 0x7fffu + ((u >> 16) & 1u);
    return (unsigned short)(u >> 16);
}

// ---------------- fp32 -> bf16 bulk convert (X) ----------------
__global__ __launch_bounds__(256) void cvt_f32_bf16(const float* __restrict__ in,
                                                    unsigned short* __restrict__ out) {
    const int i = (blockIdx.x * 256 + threadIdx.x) * 4;
    const float4v v = *(const float4v*)&in[i];
    ushort4v o;
    o.x = f2b(v.x); o.y = f2b(v.y); o.z = f2b(v.z); o.w = f2b(v.w);
    *(ushort4v*)&out[i] = o;
}

// ---------------- weight transpose+convert: W[K][N] f32 -> WT[N][K] bf16 ----------------
__global__ __launch_bounds__(256) void transpose_all(const float* __restrict__ w0,
                                                     const float* __restrict__ w1,
                                                     const float* __restrict__ w2,
                                                     const float* __restrict__ w3,
                                                     unsigned short* __restrict__ outbase) {
    __shared__ float t[64][65];
    const int z = blockIdx.z;
    const float* in = (z == 0) ? w0 : (z == 1) ? w1 : (z == 2) ? w2 : w3;
    unsigned short* out = outbase + (size_t)z * DIM * DIM;
    const int c0 = blockIdx.x * 64, r0 = blockIdx.y * 64;
    const int x = threadIdx.x, y = threadIdx.y;  // (64,4)
#pragma unroll
    for (int i = 0; i < 64; i += 4)
        t[y + i][x] = in[(size_t)(r0 + y + i) * DIM + c0 + x];
    __syncthreads();
#pragma unroll
    for (int i = 0; i < 64; i += 4)
        out[(size_t)(c0 + y + i) * DIM + r0 + x] = f2b(t[x][y + i]);
}

// ---------------- GEMM: C[m][n] = sum_k A[m][k]*BT[n][k] + bias[n] ----------------
// 128x128 tile, 4 waves (2x2 of 64x64), BK=64, pipelined staging.
// GRID IS (m-blocks=32, n-blocks=8, z): blockIdx.x = m-block so the 8 n-blocks
// (and all z) sharing an A-strip have ids congruent mod 8 -> same XCD -> the
// strip lives in that XCD's L2 instead of being HBM-fetched 8(x3) times.
// qkv=1: z=0: Q bf16 [B,H,S,Hd]; z=1: KPACK (MFMA B-frag); z=2: VPACK.
// qkv=0: fp32 row-major [M][N] out (projection).
__global__ __launch_bounds__(256) void gemm_fused(const unsigned short* __restrict__ A,
                                                  const unsigned short* __restrict__ WTbase,
                                                  const float* __restrict__ b0,
                                                  const float* __restrict__ b1,
                                                  const float* __restrict__ b2,
                                                  void* __restrict__ outbase,
                                                  int qkv) {
    __shared__ __attribute__((aligned(16))) unsigned short smem[2 * 128 * LPAD];  // 36864 B
    unsigned short* As = smem;
    unsigned short* Bs = smem + 128 * LPAD;

    const int z = blockIdx.z;
    const unsigned short* BT = WTbase + (size_t)z * (DIM * DIM);
    const float* bias        = (z == 0) ? b0 : (z == 1) ? b1 : b2;
    const int mode = qkv ? ((z == 0) ? 1 : (z == 1) ? 3 : 4) : 0;
    float* Cf          = (float*)outbase;
    unsigned short* Cb = (unsigned short*)outbase + (size_t)z * ((size_t)MTOT * DIM);

    const int tid = threadIdx.x;
    const int w = tid >> 6, lane = tid & 63;
    const int quad = lane >> 4, l16 = lane & 15;
    const int wm = w >> 1, wn = w & 1;
    const int m0 = blockIdx.x * 128, n0 = blockIdx.y * 128;  // swizzled roles
    const int bb = m0 >> 11;

    floatx4 acc[4][4];
#pragma unroll
    for (int mi = 0; mi < 4; ++mi)
#pragma unroll
        for (int ni = 0; ni < 4; ++ni) acc[mi][ni] = (floatx4)0.0f;

    const int srow = tid >> 3, scol = (tid & 7) * 8;  // staging: 8 threads/row

    short8 pa[4], pb[4];
#pragma unroll
    for (int ch = 0; ch < 4; ++ch) {
        pa[ch] = *(const short8*)&A[(size_t)(m0 + ch * 32 + srow) * DIM + scol];
        pb[ch] = *(const short8*)&BT[(size_t)(n0 + ch * 32 + srow) * DIM + scol];
    }

    for (int k0 = 0;; k0 += 64) {
#pragma unroll
        for (int ch = 0; ch < 4; ++ch) {
            *(short8*)&As[(ch * 32 + srow) * LPAD + scol] = pa[ch];
            *(short8*)&Bs[(ch * 32 + srow) * LPAD + scol] = pb[ch];
        }
        __syncthreads();
        const bool more = (k0 + 64 < DIM);
        if (more) {  // prefetch AFTER barrier; overlapped by MFMA phase below
#pragma unroll
            for (int ch = 0; ch < 4; ++ch) {
                pa[ch] = *(const short8*)&A[(size_t)(m0 + ch * 32 + srow) * DIM + k0 + 64 + scol];
                pb[ch] = *(const short8*)&BT[(size_t)(n0 + ch * 32 + srow) * DIM + k0 + 64 + scol];
            }
        }
#pragma unroll
        for (int kk = 0; kk < 2; ++kk) {
            short8 a[4], b[4];
#pragma unroll
            for (int mi = 0; mi < 4; ++mi)
                a[mi] = *(const short8*)&As[(wm * 64 + mi * 16 + l16) * LPAD + kk * 32 + quad * 8];
#pragma unroll
            for (int ni = 0; ni < 4; ++ni)
                b[ni] = *(const short8*)&Bs[(wn * 64 + ni * 16 + l16) * LPAD + kk * 32 + quad * 8];
#pragma unroll
            for (int mi = 0; mi < 4; ++mi)
#pragma unroll
                for (int ni = 0; ni < 4; ++ni)
                    acc[mi][ni] = mfma_bf16(a[mi], b[ni], acc[mi][ni]);
        }
        if (!more) break;
        __syncthreads();
    }

    float bvv[4];
#pragma unroll
    for (int ni = 0; ni < 4; ++ni) bvv[ni] = bias[n0 + wn * 64 + ni * 16 + l16];

    if (mode == 0) {
        // fp32 row-major out, 4 passes of 32 m-rows x 128 n staged in LDS
        float* T = (float*)smem;
        for (int p = 0; p < 4; ++p) {
            __syncthreads();
            if (wm == (p >> 1)) {
                const int mib = (p & 1) * 2;
#pragma unroll
                for (int mm = 0; mm < 2; ++mm)
#pragma unroll
                    for (int ni = 0; ni < 4; ++ni)
#pragma unroll
                        for (int r = 0; r < 4; ++r)
                            T[(mm * 16 + quad * 4 + r) * FPAD + wn * 64 + ni * 16 + l16] =
                                acc[mib + mm][ni][r] + bvv[ni];
            }
            __syncthreads();
#pragma unroll
            for (int it = 0; it < 4; ++it) {
                const int c = it * 256 + tid;
                const int row = c >> 5, nof = (c & 31) * 4;
                *(float4v*)&Cf[(size_t)(m0 + p * 32 + row) * DIM + n0 + nof] =
                    *(const float4v*)&T[row * FPAD + nof];
            }
        }
    } else if (mode == 1) {
        // Q: [B,H,S,Hd] bf16
        unsigned short* T = smem;
        __syncthreads();
#pragma unroll
        for (int mi = 0; mi < 4; ++mi)
#pragma unroll
            for (int ni = 0; ni < 4; ++ni)
#pragma unroll
                for (int r = 0; r < 4; ++r)
                    T[(wm * 64 + mi * 16 + quad * 4 + r) * EPAD + wn * 64 + ni * 16 + l16] =
                        f2b(acc[mi][ni][r] + bvv[ni]);
        __syncthreads();
#pragma unroll
        for (int it = 0; it < 8; ++it) {
            const int c = it * 256 + tid;
            const int seg = c >> 3, d8 = (c & 7) * 8;
            const int mm = seg >> 1, hseg = seg & 1;
            const int h = (n0 >> 6) + hseg;
            const int s = (m0 & (SEQ - 1)) + mm;
            *(short8*)&Cb[((size_t)(bb * NH + h) * SEQ + s) * HD + d8] =
                *(const short8*)&T[mm * EPAD + hseg * 64 + d8];
        }
    } else if (mode == 3) {
        // K -> KPACK: stage [s][h*64+d], then store B-frags (1KB coalesced each)
        unsigned short* T = smem;
        __syncthreads();
#pragma unroll
        for (int mi = 0; mi < 4; ++mi)
#pragma unroll
            for (int ni = 0; ni < 4; ++ni)
#pragma unroll
                for (int r = 0; r < 4; ++r)
                    T[(wm * 64 + mi * 16 + quad * 4 + r) * EPAD + wn * 64 + ni * 16 + l16] =
                        f2b(acc[mi][ni][r] + bvv[ni]);
        __syncthreads();
#pragma unroll
        for (int it = 0; it < 8; ++it) {
            const int f = it * 256 + tid;
            const int ln = f & 63, fragid = f >> 6;
            const int h2 = fragid >> 4, j2 = (fragid >> 3) & 1;
            const int ni = (fragid >> 1) & 3, kk = fragid & 1;
            const int l16f = ln & 15, quadf = ln >> 4;
            const short8 v = *(const short8*)&T[(j2 * 64 + ni * 16 + l16f) * EPAD +
                                               h2 * 64 + kk * 32 + quadf * 8];
            const int bh = bb * NH + (n0 >> 6) + h2;
            const int jg = ((m0 & (SEQ - 1)) >> 6) + j2;
            *(short8*)&Cb[(((size_t)bh * 32 + jg) * 8 + ni * 2 + kk) * 512 + ln * 8] = v;
        }
    } else {
        // V -> VPACK: stage transposed [h*64+d][s], then store PV B-frags
        unsigned short* T = smem;
        __syncthreads();
#pragma unroll
        for (int mi = 0; mi < 4; ++mi)
#pragma unroll
            for (int ni = 0; ni < 4; ++ni) {
                ushort4v pk;
#pragma unroll
                for (int r = 0; r < 4; ++r) pk[r] = f2b(acc[mi][ni][r] + bvv[ni]);
                *(ushort4v*)&T[(wn * 64 + ni * 16 + l16) * EPAD + wm * 64 + mi * 16 + quad * 4] = pk;
            }
        __syncthreads();
#pragma unroll
        for (int it = 0; it < 8; ++it) {
            const int f = it * 256 + tid;
            const int ln = f & 63, fragid = f >> 6;
            const int h2 = fragid >> 4, j2 = (fragid >> 3) & 1;
            const int ni = (fragid >> 1) & 3, kk = fragid & 1;
            const int l16f = ln & 15, quadf = ln >> 4;
            const short8 v = *(const short8*)&T[(h2 * 64 + ni * 16 + l16f) * EPAD +
                                               j2 * 64 + kk * 32 + quadf * 8];
            const int bh = bb * NH + (n0 >> 6) + h2;
            const int jg = ((m0 & (SEQ - 1)) >> 6) + j2;
            *(short8*)&Cb[(((size_t)bh * 32 + jg) * 8 + ni * 2 + kk) * 512 + ln * 8] = v;
        }
    }
}

// ---------------- causal flash attention — barrier-free, 1 wave per block ----------------
// GRID IS (bh=32, qc=64): blockIdx.x = bh so all qc-blocks of one bh have ids
// congruent mod 8 -> same XCD -> that bh's K/V frags (512 KB) stay in its L2.
// qc reversed via y (heavy blocks dispatch first).
// K/V pre-packed in MFMA B-frag order; no __syncthreads anywhere.
// Flat softmax: p = exp(s), masked -> 0, scale folded into Q.
// l via all-ones B-frag MFMA (row-sum of P) — no shuffles.
__global__ __launch_bounds__(64) void attn_fwd(const unsigned short* __restrict__ Q,
                                               const unsigned short* __restrict__ KP,
                                               const unsigned short* __restrict__ VP,
                                               unsigned short* __restrict__ O) {
    __shared__ __attribute__((aligned(16))) unsigned short Os[32 * LPAD];  // wave-private

    const int bh = blockIdx.x;
    const int qc = (gridDim.y - 1) - blockIdx.y;  // 0..63, heavy first
    const int lane = threadIdx.x;
    const int quad = lane >> 4, l16 = lane & 15;

    const unsigned short* Qh  = Q  + (size_t)bh * SEQ * HD;
    const unsigned short* KPh = KP + (size_t)bh * 32 * 4096;
    const unsigned short* VPh = VP + (size_t)bh * 32 * 4096;
    const int q0 = qc * 32;
    const int jend = qc >> 1;

    // Q fragments (A-layout), pre-scaled by Hd^-0.5 = 0.125 (exact pow2 in bf16)
    short8 qf[2][2];
#pragma unroll
    for (int mi = 0; mi < 2; ++mi)
#pragma unroll
        for (int kk = 0; kk < 2; ++kk) {
            short8 t = *(const short8*)(Qh + (size_t)(q0 + mi * 16 + l16) * HD + kk * 32 + quad * 8);
            short8 o;
#pragma unroll
            for (int e = 0; e < 8; ++e)
                o[e] = (short)f2b(b2f((unsigned short)t[e]) * 0.125f);
            qf[mi][kk] = o;
        }

    // all-ones B-frag (bf16 1.0 = 0x3F80) — layout-invariant
    short8 ones;
#pragma unroll
    for (int e = 0; e < 8; ++e) ones[e] = (short)0x3F80;

    floatx4 o_acc[2][4], l_acc[2];
#pragma unroll
    for (int mi = 0; mi < 2; ++mi) {
#pragma unroll
        for (int ni = 0; ni < 4; ++ni) o_acc[mi][ni] = (floatx4)0.0f;
        l_acc[mi] = (floatx4)0.0f;
    }

    for (int j = 0; j <= jend; ++j) {
        const unsigned short* kb = KPh + (size_t)j * 4096 + lane * 8;
        const unsigned short* vb = VPh + (size_t)j * 4096 + lane * 8;
        short8 kf[4][2], vf[4][2];
#pragma unroll
        for (int ni = 0; ni < 4; ++ni)
#pragma unroll
            for (int kk = 0; kk < 2; ++kk) {
                kf[ni][kk] = *(const short8*)(kb + (ni * 2 + kk) * 512);
                vf[ni][kk] = *(const short8*)(vb + (ni * 2 + kk) * 512);
            }

        // S = Q K^T: 32 queries x 64 keys
        floatx4 s_acc[2][4];
#pragma unroll
        for (int mi = 0; mi < 2; ++mi)
#pragma unroll
            for (int ni = 0; ni < 4; ++ni) s_acc[mi][ni] = (floatx4)0.0f;
#pragma unroll
        for (int kk = 0; kk < 2; ++kk)
#pragma unroll
            for (int ni = 0; ni < 4; ++ni)
#pragma unroll
                for (int mi = 0; mi < 2; ++mi)
                    s_acc[mi][ni] = mfma_bf16(qf[mi][kk], kf[ni][kk], s_acc[mi][ni]);

        // flat softmax + PV per m-tile (wave-private; no barriers, no shuffles)
#pragma unroll
        for (int mi = 0; mi < 2; ++mi) {
            float p[4][4];
#pragma unroll
            for (int r = 0; r < 4; ++r) {
                const int q = q0 + mi * 16 + quad * 4 + r;
#pragma unroll
                for (int ni = 0; ni < 4; ++ni) {
                    const int key = j * 64 + ni * 16 + l16;
                    p[ni][r] = (key > q) ? 0.0f : __expf(s_acc[mi][ni][r]);
                }
            }
            // P: C-layout regs -> wave-private LDS -> A-layout frags
#pragma unroll
            for (int ni = 0; ni < 4; ++ni)
#pragma unroll
                for (int r = 0; r < 4; ++r)
                    Os[(quad * 4 + r) * LPAD + ni * 16 + l16] = f2b(p[ni][r]);

#pragma unroll
            for (int kk = 0; kk < 2; ++kk) {
                const short8 pfrag = *(const short8*)&Os[l16 * LPAD + kk * 32 + quad * 8];
#pragma unroll
                for (int ni = 0; ni < 4; ++ni)
                    o_acc[mi][ni] = mfma_bf16(pfrag, vf[ni][kk], o_acc[mi][ni]);
                l_acc[mi] = mfma_bf16(pfrag, ones, l_acc[mi]);  // row-sums -> l
            }
        }
    }

    // O epilogue: normalize, stage [32 q][64 d], coalesced 16B stores
    float inv[2][4];
#pragma unroll
    for (int mi = 0; mi < 2; ++mi)
#pragma unroll
        for (int r = 0; r < 4; ++r) inv[mi][r] = 1.0f / l_acc[mi][r];
#pragma unroll
    for (int mi = 0; mi < 2; ++mi)
#pragma unroll
        for (int ni = 0; ni < 4; ++ni)
#pragma unroll
            for (int r = 0; r < 4; ++r)
                Os[(mi * 16 + quad * 4 + r) * LPAD + ni * 16 + l16] =
                    f2b(o_acc[mi][ni][r] * inv[mi][r]);
    const int bb = bh >> 4, h = bh & 15;
#pragma unroll
    for (int it = 0; it < 4; ++it) {
        const int row = it * 8 + (lane >> 3), d8 = (lane & 7) * 8;
        *(short8*)&O[(size_t)(bb * SEQ + q0 + row) * DIM + h * HD + d8] =
            *(const short8*)&Os[row * LPAD + d8];
    }
}

// ---------------- host launch ----------------
extern "C" void kernel_launch(void* const* d_in, const int* in_sizes, int n_in,
                              void* d_out, int out_size, void* d_ws, size_t ws_size,
                              hipStream_t stream) {
    // Reference dtypes are float32 — inputs and output are fp32.
    const float* X  = (const float*)d_in[0];
    const float* Wq = (const float*)d_in[1];
    const float* bq = (const float*)d_in[2];
    const float* Wk = (const float*)d_in[3];
    const float* bk = (const float*)d_in[4];
    const float* Wv = (const float*)d_in[5];
    const float* bv = (const float*)d_in[6];
    const float* Wo = (const float*)d_in[7];
    const float* bo = (const float*)d_in[8];

    unsigned short* ws = (unsigned short*)d_ws;
    const size_t WSZ = (size_t)DIM * DIM;    // 1M elems
    const size_t TSZ = (size_t)MTOT * DIM;   // 4M elems
    unsigned short* WqT = ws;                // 4 transposed weights (bf16), contiguous
    unsigned short* WoT = ws + 3 * WSZ;
    unsigned short* Qb  = ws + 4 * WSZ;      // Q [B,H,S,Hd]
    unsigned short* Kp  = Qb + TSZ;          // KPACK (B-frag order)
    unsigned short* Vp  = Kp + TSZ;          // VPACK (B-frag order)
    unsigned short* Ob  = Vp + TSZ;          // attn out [B,S,H*Hd] bf16
    // ws total: 4*2MB + 4*8MB = 40 MB

    // bf16 X in d_out[0:8MB) — dead before the final projection overwrites d_out.
    unsigned short* Xb = (unsigned short*)d_out;

    cvt_f32_bf16<<<dim3(TSZ / 1024), 256, 0, stream>>>(X, Xb);

    transpose_all<<<dim3(16, 16, 4), dim3(64, 4), 0, stream>>>(Wq, Wk, Wv, Wo, WqT);

    // fused QKV projections: Q / KPACK / VPACK (m-blocks in grid.x for XCD reuse)
    gemm_fused<<<dim3(MTOT / 128, DIM / 128, 3), 256, 0, stream>>>(
        Xb, WqT, bq, bk, bv, (void*)Qb, 1);

    // barrier-free attention, 1 wave per block (bh in grid.x for XCD K/V reuse)
    attn_fwd<<<dim3(2 * NH, SEQ / 32), 64, 0, stream>>>(Qb, Kp, Vp, Ob);

    // output projection -> fp32 d_out
    gemm_fused<<<dim3(MTOT / 128, DIM / 128, 1), 256, 0, stream>>>(
        Ob, WoT, bo, bo, bo, d_out, 0);
}